// Round 2
// baseline (1210.444 us; speedup 1.0000x reference)
//
#include <hip/hip_runtime.h>

#define BATCH 2048
#define CIN   512
#define COUT  512
#define GSZ   24
#define NORB  24
#define M_DIM (BATCH*GSZ)   // 49152
#define K_DIM (GSZ*CIN)     // 12288
#define N_DIM COUT          // 512
#define BM 128
#define BN 128
#define BK 64

typedef __bf16 bf16x8 __attribute__((ext_vector_type(8)));
typedef float  f32x4  __attribute__((ext_vector_type(4)));
typedef unsigned short u16;

__device__ __forceinline__ u16 f2bf(float f) {
  union { float f; unsigned u; } v; v.f = f;
  unsigned u = v.u;
  return (u16)((u + 0x7fffu + ((u >> 16) & 1u)) >> 16);  // RNE
}

// ---- pre-pass 1: x fp32 -> bf16 (coalesced both ways) ----
__global__ void convert_x(const float* __restrict__ x, u16* __restrict__ xb, int n4) {
  int t = blockIdx.x * blockDim.x + threadIdx.x;
  if (t >= n4) return;
  const float4 v = *(const float4*)(x + (size_t)t * 4);
  ushort4 o;
  o.x = f2bf(v.x); o.y = f2bf(v.y); o.z = f2bf(v.z); o.w = f2bf(v.w);
  *(ushort4*)(xb + (size_t)t * 4) = o;
}

// ---- pre-pass 2: weight (O,C,R) fp32 -> Bt[o][r*512+c] bf16 ----
// One block per o: coalesced float4 read -> LDS transpose -> coalesced uint4 write.
#define TROW 520  // padded row stride (u16) to spread LDS banks on scatter
__global__ void build_bt(const float* __restrict__ w, u16* __restrict__ bt) {
  __shared__ u16 lds[NORB * TROW];  // 24*520*2 = 24960 B
  const int o = blockIdx.x;
  const int t = threadIdx.x;
  const float* wo = w + (size_t)o * K_DIM;

  // phase 1: read 12288 floats as float4, scatter bf16 into LDS[r][c]
#pragma unroll
  for (int it = 0; it < 12; ++it) {
    const int idx = it * 256 + t;            // float4 index
    const float4 v = *(const float4*)(wo + idx * 4);
    const int k0 = idx * 4;                  // k = c*24 + r
#pragma unroll
    for (int e = 0; e < 4; ++e) {
      const int k = k0 + e;
      const int c = k / 24;
      const int r = k - c * 24;
      lds[r * TROW + c] = f2bf(e == 0 ? v.x : e == 1 ? v.y : e == 2 ? v.z : v.w);
    }
  }
  __syncthreads();

  // phase 2: coalesced 16B writes of bt[o][r*512+c]
  u16* bo = bt + (size_t)o * K_DIM;
#pragma unroll
  for (int it = 0; it < 6; ++it) {
    const int eidx = it * 256 + t;           // 8-elem chunk index (0..1535)
    const int base = eidx * 8;
    const int r = base >> 9;
    const int c0 = base & 511;
    const u16* src = lds + r * TROW + c0;
    uint4 v;
    v.x = src[0] | ((unsigned)src[1] << 16);
    v.y = src[2] | ((unsigned)src[3] << 16);
    v.z = src[4] | ((unsigned)src[5] << 16);
    v.w = src[6] | ((unsigned)src[7] << 16);
    *(uint4*)(bo + base) = v;
  }
}

// ---- main GEMM: C[M,512] = A[M,K] * B[K,512] + bias ----
// A[(b,i), r*512+c] = xb[b, jmap[i][r], c]  (row gather, resolved at staging)
__launch_bounds__(256, 4)
__global__ void gemm_gc(const u16* __restrict__ xb, const u16* __restrict__ bt,
                        const float* __restrict__ bias, const int* __restrict__ pair_orbit,
                        float* __restrict__ out) {
  __shared__ u16 As[BM * BK];   // 16 KB, chunk-swizzled row-major [128][64]
  __shared__ u16 Bs[BN * BK];   // 16 KB
  __shared__ int jmap[GSZ * NORB];

  const int t   = threadIdx.x;
  const int gid = blockIdx.x;
  const int m0  = (gid >> 2) * BM;
  const int n0  = (gid & 3) * BN;

  // invert pair_orbit -> jmap[i*24 + r] = j
  for (int idx = t; idx < GSZ * NORB; idx += 256) {
    int i = idx / 24;
    int j = idx - i * 24;
    jmap[i * 24 + pair_orbit[idx]] = j;
  }

  // staging setup: thread t handles LDS chunk (it*256 + t), 16 B each
  int b24[4], irow[4], aoff[4], ldsoff[4], nbase[4];
#pragma unroll
  for (int it = 0; it < 4; ++it) {
    int cidx = it * 256 + t;
    int tr   = cidx >> 3;            // tile row 0..127
    int kcs  = cidx & 7;             // stored chunk slot
    int kcg  = (kcs ^ (tr & 7)) * 8; // swizzle: which global chunk lands here (elems)
    int mrow = m0 + tr;
    int bb   = mrow / 24;
    b24[it]  = bb * 24;
    irow[it] = (mrow - bb * 24) * 24;
    aoff[it] = kcg;
    ldsoff[it] = cidx * 8;           // elems
    nbase[it]  = (n0 + tr) * K_DIM + kcg;
  }

  __syncthreads();  // jmap ready

  const int w    = t >> 6;
  const int lane = t & 63;
  const int lm   = lane & 15;
  const int q    = lane >> 4;
  const int h    = lm & 7;
  const int mw   = (w >> 1) * 64;
  const int nw   = (w & 1) * 64;

  // swizzled LDS read bases (elems); frag f adds f*1024
  const int baseA0 = ((mw + lm) * 8 + ((q)     ^ h)) * 8;
  const int baseA1 = ((mw + lm) * 8 + ((4 + q) ^ h)) * 8;
  const int baseB0 = ((nw + lm) * 8 + ((q)     ^ h)) * 8;
  const int baseB1 = ((nw + lm) * 8 + ((4 + q) ^ h)) * 8;

  f32x4 acc[4][4];
#pragma unroll
  for (int i = 0; i < 4; ++i)
#pragma unroll
    for (int j = 0; j < 4; ++j)
      acc[i][j] = (f32x4){0.f, 0.f, 0.f, 0.f};

  for (int r = 0; r < 24; ++r) {
    int arow[4];
#pragma unroll
    for (int it = 0; it < 4; ++it)
      arow[it] = (b24[it] + jmap[irow[it] + r]) * CIN + aoff[it];
    const int kr = r * 512;

    for (int kb = 0; kb < 8; ++kb) {
      const int kc0 = kb * 64;
#pragma unroll
      for (int it = 0; it < 4; ++it) {
        __builtin_amdgcn_global_load_lds(
            (__attribute__((address_space(1))) void*)(xb + arow[it] + kc0),
            (__attribute__((address_space(3))) void*)(As + ldsoff[it]), 16, 0, 0);
        __builtin_amdgcn_global_load_lds(
            (__attribute__((address_space(1))) void*)(bt + nbase[it] + kr + kc0),
            (__attribute__((address_space(3))) void*)(Bs + ldsoff[it]), 16, 0, 0);
      }
      __syncthreads();

      bf16x8 a0[4], a1[4], b0[4], b1[4];
#pragma unroll
      for (int f = 0; f < 4; ++f) {
        a0[f] = *(const bf16x8*)(As + baseA0 + f * 1024);
        a1[f] = *(const bf16x8*)(As + baseA1 + f * 1024);
        b0[f] = *(const bf16x8*)(Bs + baseB0 + f * 1024);
        b1[f] = *(const bf16x8*)(Bs + baseB1 + f * 1024);
      }
#pragma unroll
      for (int mf = 0; mf < 4; ++mf)
#pragma unroll
        for (int nf = 0; nf < 4; ++nf)
          acc[mf][nf] = __builtin_amdgcn_mfma_f32_16x16x32_bf16(a0[mf], b0[nf], acc[mf][nf], 0, 0, 0);
#pragma unroll
      for (int mf = 0; mf < 4; ++mf)
#pragma unroll
        for (int nf = 0; nf < 4; ++nf)
          acc[mf][nf] = __builtin_amdgcn_mfma_f32_16x16x32_bf16(a1[mf], b1[nf], acc[mf][nf], 0, 0, 0);
      __syncthreads();
    }
  }

  // epilogue: D row = q*4+e (m), col = lm (n); add bias[o=col]
#pragma unroll
  for (int nf = 0; nf < 4; ++nf) {
    const int col = n0 + nw + nf * 16 + lm;
    const float bv = bias[col];
#pragma unroll
    for (int mf = 0; mf < 4; ++mf) {
      const int mrow = m0 + mw + mf * 16 + q * 4;
#pragma unroll
      for (int e = 0; e < 4; ++e)
        out[(mrow + e) * N_DIM + col] = acc[mf][nf][e] + bv;
    }
  }
}

extern "C" void kernel_launch(void* const* d_in, const int* in_sizes, int n_in,
                              void* d_out, int out_size, void* d_ws, size_t ws_size,
                              hipStream_t stream) {
  (void)in_sizes; (void)n_in; (void)out_size; (void)ws_size;
  const float* x    = (const float*)d_in[0];
  const float* wgt  = (const float*)d_in[1];
  const float* bias = (const float*)d_in[2];
  const int*   po   = (const int*)d_in[3];
  float* out = (float*)d_out;

  u16* xb = (u16*)d_ws;                       // 25,165,824 elems = 50.3 MB
  u16* bt = xb + (size_t)M_DIM * CIN;         // 512*12288 elems = 12.6 MB

  const int nx4 = (BATCH * GSZ * CIN) / 4;    // 6,291,456
  convert_x<<<nx4 / 256, 256, 0, stream>>>(x, xb, nx4);
  build_bt<<<COUT, 256, 0, stream>>>(wgt, bt);

  const int grid = (M_DIM / BM) * (N_DIM / BN);  // 384*4 = 1536
  gemm_gc<<<grid, 256, 0, stream>>>(xb, bt, bias, po, out);
}

// Round 3
// 879.804 us; speedup vs baseline: 1.3758x; 1.3758x over previous
//
#include <hip/hip_runtime.h>

#define BATCH 2048
#define CIN   512
#define COUT  512
#define GSZ   24
#define NORB  24
#define M_DIM (BATCH*GSZ)   // 49152
#define K_DIM (GSZ*CIN)     // 12288
#define N_DIM COUT          // 512
#define BM 128
#define BN 128
#define BK 64

typedef __bf16 bf16x8 __attribute__((ext_vector_type(8)));
typedef float  f32x4  __attribute__((ext_vector_type(4)));
typedef unsigned short u16;

__device__ __forceinline__ u16 f2bf(float f) {
  union { float f; unsigned u; } v; v.f = f;
  unsigned u = v.u;
  return (u16)((u + 0x7fffu + ((u >> 16) & 1u)) >> 16);  // RNE
}

// ---- pre-pass 1: x fp32 -> bf16 (coalesced both ways) ----
__global__ void convert_x(const float* __restrict__ x, u16* __restrict__ xb, int n4) {
  int t = blockIdx.x * blockDim.x + threadIdx.x;
  if (t >= n4) return;
  const float4 v = *(const float4*)(x + (size_t)t * 4);
  ushort4 o;
  o.x = f2bf(v.x); o.y = f2bf(v.y); o.z = f2bf(v.z); o.w = f2bf(v.w);
  *(ushort4*)(xb + (size_t)t * 4) = o;
}

// ---- pre-pass 2: weight (O,C,R) fp32 -> Bt[o][r*512+c] bf16 ----
// One block per o: coalesced float4 read -> LDS transpose -> coalesced uint4 write.
#define TROW 520  // padded row stride (u16): breaks scatter conflicts, keeps 16B align (520%8==0)
__global__ void build_bt(const float* __restrict__ w, u16* __restrict__ bt) {
  __shared__ __align__(16) u16 lds[NORB * TROW];  // 24*520*2 = 24960 B
  const int o = blockIdx.x;
  const int t = threadIdx.x;
  const float* wo = w + (size_t)o * K_DIM;

  // phase 1: read 12288 floats as float4, scatter bf16 into LDS[r][c]
#pragma unroll
  for (int it = 0; it < 12; ++it) {
    const int idx = it * 256 + t;            // float4 index
    const float4 v = *(const float4*)(wo + idx * 4);
    const int k0 = idx * 4;                  // k = c*24 + r
#pragma unroll
    for (int e = 0; e < 4; ++e) {
      const int k = k0 + e;
      const int c = k / 24;
      const int r = k - c * 24;
      lds[r * TROW + c] = f2bf(e == 0 ? v.x : e == 1 ? v.y : e == 2 ? v.z : v.w);
    }
  }
  __syncthreads();

  // phase 2: ds_read_b128 + coalesced 16B global writes of bt[o][r*512+c]
  u16* bo = bt + (size_t)o * K_DIM;
#pragma unroll
  for (int it = 0; it < 6; ++it) {
    const int eidx = it * 256 + t;           // 8-elem chunk index (0..1535)
    const int base = eidx * 8;
    const int r = base >> 9;
    const int c0 = base & 511;
    const uint4 v = *(const uint4*)(lds + r * TROW + c0);  // 16B-aligned
    *(uint4*)(bo + base) = v;
  }
}

// ---- main GEMM: C[M,512] = A[M,K] * B[K,512] + bias ----
// A[(b,i), r*512+c] = xb[b, jmap[i][r], c]  (row gather, resolved at staging)
// NOTE: __launch_bounds__(256,3) — (256,4) clamps to 128 regs/wave and spills
// (R2: WRITE_SIZE 100->215MB, gemm 700->1050us). Natural footprint ~80V+64A.
__launch_bounds__(256, 3)
__global__ void gemm_gc(const u16* __restrict__ xb, const u16* __restrict__ bt,
                        const float* __restrict__ bias, const int* __restrict__ pair_orbit,
                        float* __restrict__ out) {
  __shared__ u16 As[BM * BK];   // 16 KB, chunk-swizzled row-major [128][64]
  __shared__ u16 Bs[BN * BK];   // 16 KB
  __shared__ int jmap[GSZ * NORB];

  const int t   = threadIdx.x;
  const int gid = blockIdx.x;
  // XCD-aware mapping (dispatch round-robin heuristic: xcd = gid % 8).
  // Each XCD owns ONE 128-col B slice (3 MB -> L2-resident).
  const int xcd = gid & 7;
  const int n0  = (xcd & 3) * BN;
  const int m0  = ((gid >> 3) * 2 + (xcd >> 2)) * BM;

  // invert pair_orbit -> jmap[i*24 + r] = j
  for (int idx = t; idx < GSZ * NORB; idx += 256) {
    int i = idx / 24;
    int j = idx - i * 24;
    jmap[i * 24 + pair_orbit[idx]] = j;
  }

  // staging setup: thread t handles LDS chunk (it*256 + t), 16 B each
  int b24[4], irow[4], aoff[4], ldsoff[4], nbase[4];
#pragma unroll
  for (int it = 0; it < 4; ++it) {
    int cidx = it * 256 + t;
    int tr   = cidx >> 3;            // tile row 0..127
    int kcs  = cidx & 7;             // stored chunk slot
    int kcg  = (kcs ^ (tr & 7)) * 8; // swizzle: which global chunk lands here (elems)
    int mrow = m0 + tr;
    int bb   = mrow / 24;
    b24[it]  = bb * 24;
    irow[it] = (mrow - bb * 24) * 24;
    aoff[it] = kcg;
    ldsoff[it] = cidx * 8;           // elems
    nbase[it]  = (n0 + tr) * K_DIM + kcg;
  }

  __syncthreads();  // jmap ready

  const int w    = t >> 6;
  const int lane = t & 63;
  const int lm   = lane & 15;
  const int q    = lane >> 4;
  const int h    = lm & 7;
  const int mw   = (w >> 1) * 64;
  const int nw   = (w & 1) * 64;

  // swizzled LDS read bases (elems); frag f adds f*1024
  const int baseA0 = ((mw + lm) * 8 + ((q)     ^ h)) * 8;
  const int baseA1 = ((mw + lm) * 8 + ((4 + q) ^ h)) * 8;
  const int baseB0 = ((nw + lm) * 8 + ((q)     ^ h)) * 8;
  const int baseB1 = ((nw + lm) * 8 + ((4 + q) ^ h)) * 8;

  f32x4 acc[4][4];
#pragma unroll
  for (int i = 0; i < 4; ++i)
#pragma unroll
    for (int j = 0; j < 4; ++j)
      acc[i][j] = (f32x4){0.f, 0.f, 0.f, 0.f};

  for (int r = 0; r < 24; ++r) {
    int arow[4];
#pragma unroll
    for (int it = 0; it < 4; ++it)
      arow[it] = (b24[it] + jmap[irow[it] + r]) * CIN + aoff[it];
    const int kr = r * 512;

    for (int kb = 0; kb < 8; ++kb) {
      const int kc0 = kb * 64;
#pragma unroll
      for (int it = 0; it < 4; ++it) {
        __builtin_amdgcn_global_load_lds(
            (__attribute__((address_space(1))) void*)(xb + arow[it] + kc0),
            (__attribute__((address_space(3))) void*)(As + ldsoff[it]), 16, 0, 0);
        __builtin_amdgcn_global_load_lds(
            (__attribute__((address_space(1))) void*)(bt + nbase[it] + kr + kc0),
            (__attribute__((address_space(3))) void*)(Bs + ldsoff[it]), 16, 0, 0);
      }
      __syncthreads();

      bf16x8 a0[4], a1[4], b0[4], b1[4];
#pragma unroll
      for (int f = 0; f < 4; ++f) {
        a0[f] = *(const bf16x8*)(As + baseA0 + f * 1024);
        a1[f] = *(const bf16x8*)(As + baseA1 + f * 1024);
        b0[f] = *(const bf16x8*)(Bs + baseB0 + f * 1024);
        b1[f] = *(const bf16x8*)(Bs + baseB1 + f * 1024);
      }
#pragma unroll
      for (int mf = 0; mf < 4; ++mf)
#pragma unroll
        for (int nf = 0; nf < 4; ++nf)
          acc[mf][nf] = __builtin_amdgcn_mfma_f32_16x16x32_bf16(a0[mf], b0[nf], acc[mf][nf], 0, 0, 0);
#pragma unroll
      for (int mf = 0; mf < 4; ++mf)
#pragma unroll
        for (int nf = 0; nf < 4; ++nf)
          acc[mf][nf] = __builtin_amdgcn_mfma_f32_16x16x32_bf16(a1[mf], b1[nf], acc[mf][nf], 0, 0, 0);
      __syncthreads();
    }
  }

  // epilogue: D row = q*4+e (m), col = lm (n); add bias[o=col]
#pragma unroll
  for (int nf = 0; nf < 4; ++nf) {
    const int col = n0 + nw + nf * 16 + lm;
    const float bv = bias[col];
#pragma unroll
    for (int mf = 0; mf < 4; ++mf) {
      const int mrow = m0 + mw + mf * 16 + q * 4;
#pragma unroll
      for (int e = 0; e < 4; ++e)
        out[(mrow + e) * N_DIM + col] = acc[mf][nf][e] + bv;
    }
  }
}

extern "C" void kernel_launch(void* const* d_in, const int* in_sizes, int n_in,
                              void* d_out, int out_size, void* d_ws, size_t ws_size,
                              hipStream_t stream) {
  (void)in_sizes; (void)n_in; (void)out_size; (void)ws_size;
  const float* x    = (const float*)d_in[0];
  const float* wgt  = (const float*)d_in[1];
  const float* bias = (const float*)d_in[2];
  const int*   po   = (const int*)d_in[3];
  float* out = (float*)d_out;

  u16* xb = (u16*)d_ws;                       // 25,165,824 elems = 50.3 MB
  u16* bt = xb + (size_t)M_DIM * CIN;         // 512*12288 elems = 12.6 MB

  const int nx4 = (BATCH * GSZ * CIN) / 4;    // 6,291,456
  convert_x<<<nx4 / 256, 256, 0, stream>>>(x, xb, nx4);
  build_bt<<<COUT, 256, 0, stream>>>(wgt, bt);

  const int grid = (M_DIM / BM) * (N_DIM / BN);  // 384*4 = 1536
  gemm_gc<<<grid, 256, 0, stream>>>(xb, bt, bias, po, out);
}